// Round 11
// baseline (850.681 us; speedup 1.0000x reference)
//
#include <hip/hip_runtime.h>

// SNN B=128, D0=512, T=512, dims 1024/1024/512, DECAY=0.5, THRESH=0.3
// Round 22 = r21 + ONE change: bit-layer LDS If-overlay-on-bits.
//  bits tile (16K, K-loop only) and If (32K, epilogue only) never coexist ->
//  overlay them. LDS 48K -> 32K => 4 blocks/CU (grid-capped) = 4 waves/SIMD
//  (was 2.2). Theory: K-loop waves stall on vmcnt for L2-latency weight
//  loads (depth-2 queue = ~512cy cover vs ~200-500cy L2 latency); doubling
//  resident waves doubles stall overlap. lb(256,4). One added barrier
//  between K-loop (bits reads) and first If dump (aliasing write).
//  K-loop, weight queue, epilogue order, MFMA sequence identical to r21
//  -> absmax=0 preserved. L0 unchanged (r16).

typedef __bf16 bf16;
typedef __attribute__((ext_vector_type(8))) __bf16 bf16x8;
typedef __attribute__((ext_vector_type(16))) float f32x16;
typedef unsigned long long u64;

#define B_   128
#define D0_  512
#define T_   512
#define TS_  128
#define N1_  1024
#define N2_  1024
#define N3_  512
#define MFMA32(a,b,c) __builtin_amdgcn_mfma_f32_32x32x16_bf16((a),(b),(c),0,0,0)

#define GL2LDS(g, l) __builtin_amdgcn_global_load_lds( \
    (const __attribute__((address_space(1))) void*)(g), \
    (__attribute__((address_space(3))) void*)(l), 16, 0, 0)

#define WAIT_BARRIER() do { \
    asm volatile("s_waitcnt vmcnt(0)" ::: "memory"); \
    __builtin_amdgcn_s_barrier(); } while (0)

// ---------- setup ----------

__global__ __launch_bounds__(256)
void split_w(const float* __restrict__ W, bf16* __restrict__ WTh, bf16* __restrict__ WTl,
             int K, int N)
{
    __shared__ float tile[32][33];
    const int k0 = blockIdx.x * 32, n0 = blockIdx.y * 32;
    const int tx = threadIdx.x & 31, ty = threadIdx.x >> 5;
#pragma unroll
    for (int r = 0; r < 4; ++r)
        tile[ty + r * 8][tx] = W[(size_t)(k0 + ty + r * 8) * N + n0 + tx];
    __syncthreads();
#pragma unroll
    for (int r = 0; r < 4; ++r) {
        int nl = ty + r * 8;
        float v = tile[tx][nl];
        bf16 h = (bf16)v;
        size_t o = (size_t)(n0 + nl) * K + k0 + tx;
        WTh[o] = h;
        WTl[o] = (bf16)(v - (float)h);
    }
}

// W [K][N] fp32 -> fragment-major WF[N/32][K/16][lane 64][8] bf16 hi/lo.
__global__ __launch_bounds__(64)
void split_wf(const float* __restrict__ W, bf16* __restrict__ Fh, bf16* __restrict__ Fl,
              int K, int N)
{
    const int l = threadIdx.x;
    const int kc = blockIdx.x;           // K/16 blocks
    const int np = blockIdx.y;           // N/32 blocks
    const int c  = np * 32 + (l & 31);
    const int k0 = kc * 16 + (l >> 5) * 8;
    const size_t ob = (((size_t)np * (K / 16) + kc) * 64 + l) * 8;
#pragma unroll
    for (int e = 0; e < 8; ++e) {
        float v = W[(size_t)(k0 + e) * N + c];
        bf16 h = (bf16)v;
        Fh[ob + e] = h;
        Fl[ob + e] = (bf16)(v - (float)h);
    }
}

// x [B][D0][T] fp32 -> Xh/Xl slice-major [s][b][tl][D0] bf16 (hi/lo)
__global__ __launch_bounds__(256)
void split_x(const float* __restrict__ in, bf16* __restrict__ Xh, bf16* __restrict__ Xl)
{
    __shared__ float tile[32][33];
    const int b = blockIdx.z, d0 = blockIdx.x * 32, t0 = blockIdx.y * 32;
    const int tx = threadIdx.x & 31, ty = threadIdx.x >> 5;
#pragma unroll
    for (int r = 0; r < 4; ++r)
        tile[ty + r * 8][tx] = in[((size_t)b * D0_ + d0 + ty + r * 8) * T_ + t0 + tx];
    __syncthreads();
    const int s = t0 >> 7;
#pragma unroll
    for (int r = 0; r < 4; ++r) {
        int t  = t0 + ty + r * 8;
        int tl = t & (TS_ - 1);
        float v = tile[tx][ty + r * 8];
        bf16 h = (bf16)v;
        size_t o = (((size_t)s * B_ + b) * TS_ + tl) * D0_ + d0 + tx;
        Xh[o] = h;
        Xl[o] = (bf16)(v - (float)h);
    }
}

// 8 bits -> bf16x8 of {0.0, 1.0} (exact).
__device__ __forceinline__ bf16x8 expand8(unsigned v)
{
    union { unsigned u[4]; bf16x8 h; } r;
    const unsigned p = v * 0x8001u;
#pragma unroll
    for (int i = 0; i < 4; ++i)
        r.u[i] = ((p >> (2 * i)) & 0x10001u) * 0x3F80u;
    return r.h;
}

// ---------- layer 0: Xh/Xl @ W0 (3-term), BK=32, 2-phase dbuf (r16) ----------
__global__ __launch_bounds__(256, 2)
void snn_layer0(const bf16* __restrict__ Ah, const bf16* __restrict__ Al,
                const bf16* __restrict__ WTh, const bf16* __restrict__ WTl,
                u64* __restrict__ bitsOut)
{
    constexpr int K = D0_;
    __shared__ char smem[65536];
    bf16* sA0  = (bf16*)(smem);
    bf16* sAl0 = (bf16*)(smem + 8192);
    bf16* sB0  = (bf16*)(smem + 16384);
    bf16* sBl0 = (bf16*)(smem + 24576);
    bf16* sA1  = (bf16*)(smem + 32768);
    bf16* sAl1 = (bf16*)(smem + 40960);
    bf16* sB1  = (bf16*)(smem + 49152);
    bf16* sBl1 = (bf16*)(smem + 57344);
    float* If  = (float*)smem;

    const int tid = threadIdx.x, lane = tid & 63, w = tid >> 6;
    const int wm = w & 1, wn = w >> 1;
    const int l31 = lane & 31, kh = lane >> 5;
    const int bid = blockIdx.x;
    const int b  = (bid & 7) | ((bid >> 6) << 3);    // bid%8 + 8*(bid/64)
    const int nb = ((bid >> 3) & 7) * 128;

    const int i4 = lane >> 2, c4 = lane & 3;
    const int csrc = c4 ^ ((i4 >> 1) & 3);
    const bf16* gBh = WTh + (size_t)(nb + w * 32 + i4) * K + csrc * 8;
    const bf16* gBl = WTl + (size_t)(nb + w * 32 + i4) * K + csrc * 8;
    const int wT = w * 32 * 32;

    int rA[2], rB[2], swA[2], swB[2];
#pragma unroll
    for (int i = 0; i < 2; ++i) {
        rA[i] = wm * 64 + i * 32 + l31;
        rB[i] = wn * 64 + i * 32 + l31;
        swA[i] = (rA[i] >> 1) & 3;
        swB[i] = (rB[i] >> 1) & 3;
    }

    float cm = 0.f, cs = 0.f;
    const int scol = tid & 63;
    float* Ifb = If + (tid >> 6) * 4096;

#define STAGE0(dA, dAl, dBh, dBl, go)                                          \
    do {                                                                       \
        _Pragma("unroll")                                                      \
        for (int inst = 0; inst < 2; ++inst) {                                 \
            GL2LDS(gA  + (size_t)(inst * 16) * K + (go), (dA)  + wT + inst * 16 * 32); \
            GL2LDS(gAl + (size_t)(inst * 16) * K + (go), (dAl) + wT + inst * 16 * 32); \
            GL2LDS(gBh + (size_t)(inst * 16) * K + (go), (dBh) + wT + inst * 16 * 32); \
            GL2LDS(gBl + (size_t)(inst * 16) * K + (go), (dBl) + wT + inst * 16 * 32); \
        }                                                                      \
    } while (0)

#define KSTEP0(cA, cAl, cBh, cBl)                                              \
    do {                                                                       \
        bf16x8 a[2][2], al2[2][2];                                             \
        _Pragma("unroll")                                                      \
        for (int mi = 0; mi < 2; ++mi)                                         \
            _Pragma("unroll")                                                  \
            for (int h = 0; h < 2; ++h) {                                      \
                const int off = rA[mi] * 32 + (((2 * h + kh) ^ swA[mi]) * 8);  \
                a[mi][h]   = *(const bf16x8*)((cA) + off);                     \
                al2[mi][h] = *(const bf16x8*)((cAl) + off);                    \
            }                                                                  \
        _Pragma("unroll")                                                      \
        for (int h = 0; h < 2; ++h) {                                          \
            bf16x8 bh[2], bl[2];                                               \
            _Pragma("unroll")                                                  \
            for (int ni = 0; ni < 2; ++ni) {                                   \
                const int off = rB[ni] * 32 + (((2 * h + kh) ^ swB[ni]) * 8);  \
                bh[ni] = *(const bf16x8*)((cBh) + off);                        \
                bl[ni] = *(const bf16x8*)((cBl) + off);                        \
            }                                                                  \
            _Pragma("unroll")                                                  \
            for (int ni = 0; ni < 2; ++ni)                                     \
                _Pragma("unroll")                                              \
                for (int mi = 0; mi < 2; ++mi)                                 \
                    acc[mi][ni] = MFMA32(a[mi][h], bh[ni], acc[mi][ni]);       \
            _Pragma("unroll")                                                  \
            for (int ni = 0; ni < 2; ++ni)                                     \
                _Pragma("unroll")                                              \
                for (int mi = 0; mi < 2; ++mi)                                 \
                    acc[mi][ni] = MFMA32(al2[mi][h], bh[ni], acc[mi][ni]);     \
            _Pragma("unroll")                                                  \
            for (int ni = 0; ni < 2; ++ni)                                     \
                _Pragma("unroll")                                              \
                for (int mi = 0; mi < 2; ++mi)                                 \
                    acc[mi][ni] = MFMA32(a[mi][h], bl[ni], acc[mi][ni]);       \
        }                                                                      \
        WAIT_BARRIER();                                                        \
    } while (0)

#pragma unroll 1
    for (int s = 0; s < T_ / TS_; ++s) {
        const size_t arow = ((size_t)s * B_ + b) * TS_;
        const bf16* gA  = Ah + (arow + w * 32 + i4) * K + csrc * 8;
        const bf16* gAl = Al + (arow + w * 32 + i4) * K + csrc * 8;

        STAGE0(sA0, sAl0, sB0, sBl0, 0);
        WAIT_BARRIER();

        f32x16 acc[2][2] = {};

#pragma unroll 1
        for (int ks = 0; ks < K / 32; ks += 2) {
            STAGE0(sA1, sAl1, sB1, sBl1, (ks + 1) * 32);
            KSTEP0(sA0, sAl0, sB0, sBl0);
            if (ks + 2 < K / 32)
                STAGE0(sA0, sAl0, sB0, sBl0, (ks + 2) * 32);
            KSTEP0(sA1, sAl1, sB1, sBl1);
        }

        u64 word0 = 0, word1 = 0;
        if (wm == 0) {
#pragma unroll
            for (int ni = 0; ni < 2; ++ni)
#pragma unroll
                for (int mi = 0; mi < 2; ++mi)
#pragma unroll
                    for (int r = 0; r < 16; ++r) {
                        const int tt = mi * 32 + (r & 3) + 8 * (r >> 2) + 4 * kh;
                        If[wn * 4096 + tt * 64 + ni * 32 + l31] = acc[mi][ni][r];
                    }
        }
        __syncthreads();
        if (tid < 128) {
            float m = cm, sp = cs;
#pragma unroll 4
            for (int tt = 0; tt < 64; ++tt) {
                m = m * 0.5f * (1.0f - sp) + Ifb[tt * 64 + scol];
                const bool fire = m > 0.3f;
                sp = fire ? 1.0f : 0.0f;
                u64 bal = __ballot(fire);
                if ((tid & 63) == tt) word0 = bal;
            }
            cm = m; cs = sp;
        }
        __syncthreads();
        if (wm == 1) {
#pragma unroll
            for (int ni = 0; ni < 2; ++ni)
#pragma unroll
                for (int mi = 0; mi < 2; ++mi)
#pragma unroll
                    for (int r = 0; r < 16; ++r) {
                        const int tt = mi * 32 + (r & 3) + 8 * (r >> 2) + 4 * kh;
                        If[wn * 4096 + tt * 64 + ni * 32 + l31] = acc[mi][ni][r];
                    }
        }
        __syncthreads();
        if (tid < 128) {
            float m = cm, sp = cs;
#pragma unroll 4
            for (int tt = 0; tt < 64; ++tt) {
                m = m * 0.5f * (1.0f - sp) + Ifb[tt * 64 + scol];
                const bool fire = m > 0.3f;
                sp = fire ? 1.0f : 0.0f;
                u64 bal = __ballot(fire);
                if ((tid & 63) == tt) word1 = bal;
            }
            cm = m; cs = sp;
            u64* dst = bitsOut + ((size_t)s * B_ + b) * 2048;
            const int j8 = (nb >> 6) + (tid >> 6);
            const int t0 = tid & 63, t1 = 64 + (tid & 63);
            dst[t0 * 16 + (j8 ^ (t0 & 15))] = word0;
            dst[t1 * 16 + (j8 ^ (t1 & 15))] = word1;
        }
        __syncthreads();
    }
#undef STAGE0
#undef KSTEP0
}

// ---------- bit-layers: 2x2 ownership, direct-register weight queue ----------
// Wave (wm,wn): t rows wm*64 + {0,32} + l31; cols nb + wn*64 + {0,32} + l31.
// LDS 32 KB: bits [0,16K) used in K-loop; If [0,32K) overlays it in epilogue.
template<bool WRITE_BITS>
__global__ __launch_bounds__(256, 4)
void snn_layer_bits(const u64* __restrict__ bitsIn,
                    const bf16* __restrict__ WFh, const bf16* __restrict__ WFl,
                    u64* __restrict__ bitsOut, float* __restrict__ outp, int N)
{
    constexpr int K = 1024, KC = K / 16;        // 64 k-chunks, 16 pairs
    __shared__ char smem[32768];
    char* bitsLds = smem;                       // [0,16K): bit tile (K-loop only)
    float* If = (float*)smem;                   // [0,32K): epilogue overlay

    const int tid = threadIdx.x, lane = tid & 63, w = tid >> 6;
    const int wm = w & 1, wn = w >> 1;
    const int l31 = lane & 31, kh = lane >> 5;
    const int b = blockIdx.y;
    const int nb = blockIdx.x * 128;

    // fragment bases: np0 = nb/32 + wn*2, np1 = np0 + 1
    const size_t fb0 = ((size_t)((nb >> 5) + wn * 2) * KC) * 512 + (size_t)lane * 8;
    const size_t fb1 = fb0 + (size_t)KC * 512;
    const bf16* h0 = WFh + fb0;
    const bf16* h1 = WFh + fb1;
    const bf16* l0 = WFl + fb0;
    const bf16* l1 = WFl + fb1;

    const int sh8 = 8 * kh, s15 = l31 & 15;
    const int rA0b = (wm * 64 + l31) * 128;
    const int rA1b = (wm * 64 + 32 + l31) * 128;

    float cm = 0.f, cs = 0.f;
    const int scol = tid & 63;
    float* Ifb = If + (tid >> 6) * 4096;

#define LOADQ(sl, kc)                                                          \
    do {                                                                       \
        q0h[sl] = *(const bf16x8*)(h0 + (size_t)(kc) * 512);                   \
        q1h[sl] = *(const bf16x8*)(h1 + (size_t)(kc) * 512);                   \
        q0l[sl] = *(const bf16x8*)(l0 + (size_t)(kc) * 512);                   \
        q1l[sl] = *(const bf16x8*)(l1 + (size_t)(kc) * 512);                   \
    } while (0)

// 8 MFMAs of one j-step; per-acc order: (pi asc, j asc, hi before lo) == r13
#define JSTEP(j, CB0, CB1)                                                     \
    do {                                                                       \
        bf16x8 a0 = expand8((unsigned)((CB0) >> (16 * (j) + sh8)) & 0xFFu);    \
        bf16x8 a1 = expand8((unsigned)((CB1) >> (16 * (j) + sh8)) & 0xFFu);    \
        acc[0][0] = MFMA32(a0, q0h[j], acc[0][0]);                             \
        acc[1][0] = MFMA32(a1, q0h[j], acc[1][0]);                             \
        acc[0][1] = MFMA32(a0, q1h[j], acc[0][1]);                             \
        acc[1][1] = MFMA32(a1, q1h[j], acc[1][1]);                             \
        acc[0][0] = MFMA32(a0, q0l[j], acc[0][0]);                             \
        acc[1][0] = MFMA32(a1, q0l[j], acc[1][0]);                             \
        acc[0][1] = MFMA32(a0, q1l[j], acc[0][1]);                             \
        acc[1][1] = MFMA32(a1, q1l[j], acc[1][1]);                             \
    } while (0)

#pragma unroll 1
    for (int s = 0; s < T_ / TS_; ++s) {
        // stage bit tile (16 KB, 4 GL2LDS/wave)
        {
            const char* src = (const char*)bitsIn + ((size_t)s * B_ + b) * 16384;
#pragma unroll
            for (int i = 0; i < 4; ++i)
                GL2LDS(src + (w * 4 + i) * 1024 + lane * 16,
                       bitsLds + (w * 4 + i) * 1024);
        }
        WAIT_BARRIER();                 // bits visible to all waves

        f32x16 acc[2][2] = {};
        bf16x8 q0h[4], q0l[4], q1h[4], q1l[4];

        // prologue: queue kc=0,1; bits pair 0
        LOADQ(0, 0);
        LOADQ(1, 1);
        u64 cb0 = *(const u64*)(bitsLds + rA0b + ((0 ^ s15) << 3));
        u64 cb1 = *(const u64*)(bitsLds + rA1b + ((0 ^ s15) << 3));

        // main: pairs 0..14 (unguarded prefetch), no barriers
#pragma unroll 1
        for (int pi = 0; pi < 15; ++pi) {
            const u64 nb0 = *(const u64*)(bitsLds + rA0b + (((pi + 1) ^ s15) << 3));
            const u64 nb1 = *(const u64*)(bitsLds + rA1b + (((pi + 1) ^ s15) << 3));
            const int kc = pi * 4;
            LOADQ(2, kc + 2); JSTEP(0, cb0, cb1);
            LOADQ(3, kc + 3); JSTEP(1, cb0, cb1);
            LOADQ(0, kc + 4); JSTEP(2, cb0, cb1);
            LOADQ(1, kc + 5); JSTEP(3, cb0, cb1);
            cb0 = nb0; cb1 = nb1;
        }
        // pair 15 (peeled: only kc 62,63 left to load)
        LOADQ(2, 62); JSTEP(0, cb0, cb1);
        LOADQ(3, 63); JSTEP(1, cb0, cb1);
        JSTEP(2, cb0, cb1);
        JSTEP(3, cb0, cb1);

        // ---- epilogue: r13's verified 2-phase LIF scan (If overlays bits) ----
        __syncthreads();                 // all waves done reading bits
        u64 word0 = 0, word1 = 0;
        if (wm == 0) {
#pragma unroll
            for (int ni = 0; ni < 2; ++ni)
#pragma unroll
                for (int mi = 0; mi < 2; ++mi)
#pragma unroll
                    for (int r = 0; r < 16; ++r) {
                        const int tt = mi * 32 + (r & 3) + 8 * (r >> 2) + 4 * kh;
                        If[wn * 4096 + tt * 64 + ni * 32 + l31] = acc[mi][ni][r];
                    }
        }
        __syncthreads();
        if (tid < 128) {
            float m = cm, sp = cs;
#pragma unroll 4
            for (int tt = 0; tt < 64; ++tt) {
                m = m * 0.5f * (1.0f - sp) + Ifb[tt * 64 + scol];
                const bool fire = m > 0.3f;
                sp = fire ? 1.0f : 0.0f;
                if constexpr (WRITE_BITS) {
                    u64 bal = __ballot(fire);
                    if ((tid & 63) == tt) word0 = bal;
                }
            }
            cm = m; cs = sp;
        }
        __syncthreads();
        if (wm == 1) {
#pragma unroll
            for (int ni = 0; ni < 2; ++ni)
#pragma unroll
                for (int mi = 0; mi < 2; ++mi)
#pragma unroll
                    for (int r = 0; r < 16; ++r) {
                        const int tt = mi * 32 + (r & 3) + 8 * (r >> 2) + 4 * kh;
                        If[wn * 4096 + tt * 64 + ni * 32 + l31] = acc[mi][ni][r];
                    }
        }
        __syncthreads();
        if (tid < 128) {
            float m = cm, sp = cs;
#pragma unroll 4
            for (int tt = 0; tt < 64; ++tt) {
                m = m * 0.5f * (1.0f - sp) + Ifb[tt * 64 + scol];
                const bool fire = m > 0.3f;
                sp = fire ? 1.0f : 0.0f;
                if constexpr (WRITE_BITS) {
                    u64 bal = __ballot(fire);
                    if ((tid & 63) == tt) word1 = bal;
                }
            }
            cm = m; cs = sp;
            if constexpr (WRITE_BITS) {
                u64* dst = bitsOut + ((size_t)s * B_ + b) * 2048;
                const int j8 = (nb >> 6) + (tid >> 6);
                const int t0 = tid & 63, t1 = 64 + (tid & 63);
                dst[t0 * 16 + (j8 ^ (t0 & 15))] = word0;
                dst[t1 * 16 + (j8 ^ (t1 & 15))] = word1;
            } else {
                if (s == T_ / TS_ - 1)
                    outp[(size_t)b * N + nb + tid] = cs;   // spike at t=511
            }
        }
        __syncthreads();                 // If reads done before next slice
    }
#undef LOADQ
#undef JSTEP
}

extern "C" void kernel_launch(void* const* d_in, const int* in_sizes, int n_in,
                              void* d_out, int out_size, void* d_ws, size_t ws_size,
                              hipStream_t stream)
{
    const float* x  = (const float*)d_in[0];
    const float* w0 = (const float*)d_in[1];
    const float* w1 = (const float*)d_in[2];
    const float* w2 = (const float*)d_in[3];
    float* out = (float*)d_out;

    char* p = (char*)d_ws;
    bf16* w0h  = (bf16*)p; p += (size_t)N1_ * D0_ * 2;
    bf16* w0l  = (bf16*)p; p += (size_t)N1_ * D0_ * 2;
    bf16* wf1h = (bf16*)p; p += (size_t)N2_ * N1_ * 2;
    bf16* wf1l = (bf16*)p; p += (size_t)N2_ * N1_ * 2;
    bf16* wf2h = (bf16*)p; p += (size_t)N3_ * N2_ * 2;
    bf16* wf2l = (bf16*)p; p += (size_t)N3_ * N2_ * 2;
    bf16* Xh   = (bf16*)p; p += (size_t)T_ * B_ * D0_ * 2;          // 67 MB
    bf16* Xl   = (bf16*)p; p += (size_t)T_ * B_ * D0_ * 2;          // 67 MB
    u64* bits0 = (u64*)p;  p += (size_t)(T_/TS_) * B_ * TS_ * (N1_/8);  // 8.4 MB
    u64* bits1 = (u64*)p;  p += (size_t)(T_/TS_) * B_ * TS_ * (N2_/8);  // 8.4 MB

    split_w<<<dim3(D0_/32, N1_/32), 256, 0, stream>>>(w0, w0h, w0l, D0_, N1_);
    split_wf<<<dim3(N1_/16, N2_/32), 64, 0, stream>>>(w1, wf1h, wf1l, N1_, N2_);
    split_wf<<<dim3(N2_/16, N3_/32), 64, 0, stream>>>(w2, wf2h, wf2l, N2_, N3_);
    split_x<<<dim3(D0_/32, T_/32, B_), 256, 0, stream>>>(x, Xh, Xl);

    // L0: X@w0 (3-term split) + LIF -> bit train (XCD-grouped flat grid)
    snn_layer0<<<dim3(B_ * (N1_/128)), 256, 0, stream>>>(Xh, Xl, w0h, w0l, bits0);
    // L1: bits0@w1 + LIF -> bit train
    snn_layer_bits<true ><<<dim3(N2_/128, B_), 256, 0, stream>>>(
        bits0, wf1h, wf1l, bits1, nullptr, N2_);
    // L2: bits1@w2 + LIF -> final spikes to d_out
    snn_layer_bits<false><<<dim3(N3_/128, B_), 256, 0, stream>>>(
        bits1, wf2h, wf2l, nullptr, out, N3_);
}

// Round 12
// 795.111 us; speedup vs baseline: 1.0699x; 1.0699x over previous
//
#include <hip/hip_runtime.h>

// SNN B=128, D0=512, T=512, dims 1024/1024/512, DECAY=0.5, THRESH=0.3
// Round 23: L0 rewritten in the r21 direct-register style.
//  - X pre-laid fragment-major by split_xf: XF[s][b][tb4][kc32][lane64][8]
//    hi/lo; W0 fragment-major via split_wf. L0 K-loop: 2-slot ping-pong
//    register queue (8 frags/slot), 12 MFMA per kc (3-term hh/lh/hl),
//    ZERO barriers, ZERO LDS staging; LDS = 32KB If only.
//  - Per-acc chain order (kc asc; hh->lh->hl) identical to r16 L0 ->
//    absmax=0 preserved. split_w deleted.
//  - L1/L2 bit-layers = r21 verbatim (best measured: 262 us; r22's
//    higher-occupancy variant regressed and is reverted).

typedef __bf16 bf16;
typedef __attribute__((ext_vector_type(8))) __bf16 bf16x8;
typedef __attribute__((ext_vector_type(16))) float f32x16;
typedef unsigned long long u64;

#define B_   128
#define D0_  512
#define T_   512
#define TS_  128
#define N1_  1024
#define N2_  1024
#define N3_  512
#define MFMA32(a,b,c) __builtin_amdgcn_mfma_f32_32x32x16_bf16((a),(b),(c),0,0,0)

#define GL2LDS(g, l) __builtin_amdgcn_global_load_lds( \
    (const __attribute__((address_space(1))) void*)(g), \
    (__attribute__((address_space(3))) void*)(l), 16, 0, 0)

#define WAIT_BARRIER() do { \
    asm volatile("s_waitcnt vmcnt(0)" ::: "memory"); \
    __builtin_amdgcn_s_barrier(); } while (0)

// ---------- setup ----------

// W [K][N] fp32 -> fragment-major WF[N/32][K/16][lane 64][8] bf16 hi/lo.
// Element (np,kc,l,e): col = np*32 + (l&31), k = kc*16 + (l>>5)*8 + e.
__global__ __launch_bounds__(64)
void split_wf(const float* __restrict__ W, bf16* __restrict__ Fh, bf16* __restrict__ Fl,
              int K, int N)
{
    const int l = threadIdx.x;
    const int kc = blockIdx.x;           // K/16 blocks
    const int np = blockIdx.y;           // N/32 blocks
    const int c  = np * 32 + (l & 31);
    const int k0 = kc * 16 + (l >> 5) * 8;
    const size_t ob = (((size_t)np * (K / 16) + kc) * 64 + l) * 8;
#pragma unroll
    for (int e = 0; e < 8; ++e) {
        float v = W[(size_t)(k0 + e) * N + c];
        bf16 h = (bf16)v;
        Fh[ob + e] = h;
        Fl[ob + e] = (bf16)(v - (float)h);
    }
}

// x [B][D0][T] fp32 -> A-fragment-major XF[s*B+b][tb 4][kc 32][lane 64][8]
// hi/lo. Element: t(slice-local) = tb*32 + (l&31), k = kc*16 + (l>>5)*8 + e.
__global__ __launch_bounds__(64)
void split_xf(const float* __restrict__ in, bf16* __restrict__ Fh, bf16* __restrict__ Fl)
{
    const int l  = threadIdx.x;
    const int kc = blockIdx.x;           // 0..31
    const int tb = blockIdx.y;           // 0..3
    const int sb = blockIdx.z;           // 0..511 = s*B + b
    const int s = sb >> 7, b = sb & 127;
    const int t  = s * TS_ + tb * 32 + (l & 31);
    const int k0 = kc * 16 + (l >> 5) * 8;
    const size_t ob = (((size_t)sb * 4 + tb) * 32 + kc) * 512 + (size_t)l * 8;
#pragma unroll
    for (int e = 0; e < 8; ++e) {
        float v = in[((size_t)b * D0_ + k0 + e) * T_ + t];
        bf16 h = (bf16)v;
        Fh[ob + e] = h;
        Fl[ob + e] = (bf16)(v - (float)h);
    }
}

// 8 bits -> bf16x8 of {0.0, 1.0} (exact).
__device__ __forceinline__ bf16x8 expand8(unsigned v)
{
    union { unsigned u[4]; bf16x8 h; } r;
    const unsigned p = v * 0x8001u;
#pragma unroll
    for (int i = 0; i < 4; ++i)
        r.u[i] = ((p >> (2 * i)) & 0x10001u) * 0x3F80u;
    return r.h;
}

// ---------- layer 0: direct-register 3-term GEMM + LIF ----------
// Wave (wm,wn): t rows wm*64 + {0,32} + l31 (tb = wm*2+{0,1});
// cols nb + wn*64 + {0,32} + l31 (np = nb/32 + wn*2 + {0,1}).
// K-loop: 32 kc, 2-slot ping-pong queue {a0,a1,al0,al1,b0,b1,bl0,bl1},
// 12 MFMA/kc, no barriers. LDS = 32KB If (epilogue only).
__global__ __launch_bounds__(256, 2)
void snn_layer0(const bf16* __restrict__ XFh, const bf16* __restrict__ XFl,
                const bf16* __restrict__ WFh, const bf16* __restrict__ WFl,
                u64* __restrict__ bitsOut)
{
    constexpr int KC0 = D0_ / 16;               // 32 k-chunks
    __shared__ float If[8192];                  // 32 KB [2][64][64]

    const int tid = threadIdx.x, lane = tid & 63, w = tid >> 6;
    const int wm = w & 1, wn = w >> 1;
    const int l31 = lane & 31, kh = lane >> 5;
    const int bid = blockIdx.x;
    const int b  = (bid & 7) | ((bid >> 6) << 3);    // XCD-grouped (r16)
    const int nb = ((bid >> 3) & 7) * 128;

    // B fragment pointers (loop-invariant)
    const size_t fb0 = ((size_t)((nb >> 5) + wn * 2) * KC0) * 512 + (size_t)lane * 8;
    const bf16* b0h = WFh + fb0;
    const bf16* b1h = b0h + (size_t)KC0 * 512;
    const bf16* b0l = WFl + fb0;
    const bf16* b1l = b0l + (size_t)KC0 * 512;

    float cm = 0.f, cs = 0.f;
    const int scol = tid & 63;
    float* Ifb = If + (tid >> 6) * 4096;

#define LOADF(sl, kc)                                                          \
    do {                                                                       \
        qah[sl][0] = *(const bf16x8*)(a0h + (size_t)(kc) * 512);               \
        qah[sl][1] = *(const bf16x8*)(a1h + (size_t)(kc) * 512);               \
        qal[sl][0] = *(const bf16x8*)(a0l + (size_t)(kc) * 512);               \
        qal[sl][1] = *(const bf16x8*)(a1l + (size_t)(kc) * 512);               \
        qbh[sl][0] = *(const bf16x8*)(b0h + (size_t)(kc) * 512);               \
        qbh[sl][1] = *(const bf16x8*)(b1h + (size_t)(kc) * 512);               \
        qbl[sl][0] = *(const bf16x8*)(b0l + (size_t)(kc) * 512);               \
        qbl[sl][1] = *(const bf16x8*)(b1l + (size_t)(kc) * 512);               \
    } while (0)

// 12 MFMA of one kc; per-acc chain order: hh, lh, hl (== r16 L0)
#define COMPUTEF(sl)                                                           \
    do {                                                                       \
        acc[0][0] = MFMA32(qah[sl][0], qbh[sl][0], acc[0][0]);                 \
        acc[1][0] = MFMA32(qah[sl][1], qbh[sl][0], acc[1][0]);                 \
        acc[0][1] = MFMA32(qah[sl][0], qbh[sl][1], acc[0][1]);                 \
        acc[1][1] = MFMA32(qah[sl][1], qbh[sl][1], acc[1][1]);                 \
        acc[0][0] = MFMA32(qal[sl][0], qbh[sl][0], acc[0][0]);                 \
        acc[1][0] = MFMA32(qal[sl][1], qbh[sl][0], acc[1][0]);                 \
        acc[0][1] = MFMA32(qal[sl][0], qbh[sl][1], acc[0][1]);                 \
        acc[1][1] = MFMA32(qal[sl][1], qbh[sl][1], acc[1][1]);                 \
        acc[0][0] = MFMA32(qah[sl][0], qbl[sl][0], acc[0][0]);                 \
        acc[1][0] = MFMA32(qah[sl][1], qbl[sl][0], acc[1][0]);                 \
        acc[0][1] = MFMA32(qah[sl][0], qbl[sl][1], acc[0][1]);                 \
        acc[1][1] = MFMA32(qah[sl][1], qbl[sl][1], acc[1][1]);                 \
    } while (0)

#pragma unroll 1
    for (int s = 0; s < T_ / TS_; ++s) {
        // A fragment pointers for this slice (wave's 2 t-blocks)
        const size_t ab = ((size_t)(s * B_ + b) * 4 + wm * 2) * ((size_t)KC0 * 512)
                          + (size_t)lane * 8;
        const bf16* a0h = XFh + ab;
        const bf16* a1h = a0h + (size_t)KC0 * 512;
        const bf16* a0l = XFl + ab;
        const bf16* a1l = a0l + (size_t)KC0 * 512;

        f32x16 acc[2][2] = {};
        bf16x8 qah[2][2], qal[2][2], qbh[2][2], qbl[2][2];

        LOADF(0, 0);
        LOADF(1, 1);
#pragma unroll 1
        for (int kc = 0; kc < 30; kc += 2) {
            COMPUTEF(0);
            LOADF(0, kc + 2);
            COMPUTEF(1);
            LOADF(1, kc + 3);
        }
        COMPUTEF(0);                    // kc = 30
        COMPUTEF(1);                    // kc = 31

        // ---- epilogue: 2-phase LIF scan + ballot bit store (r21 structure) ----
        u64 word0 = 0, word1 = 0;
        if (wm == 0) {
#pragma unroll
            for (int ni = 0; ni < 2; ++ni)
#pragma unroll
                for (int mi = 0; mi < 2; ++mi)
#pragma unroll
                    for (int r = 0; r < 16; ++r) {
                        const int tt = mi * 32 + (r & 3) + 8 * (r >> 2) + 4 * kh;
                        If[wn * 4096 + tt * 64 + ni * 32 + l31] = acc[mi][ni][r];
                    }
        }
        __syncthreads();
        if (tid < 128) {
            float m = cm, sp = cs;
#pragma unroll 4
            for (int tt = 0; tt < 64; ++tt) {
                m = m * 0.5f * (1.0f - sp) + Ifb[tt * 64 + scol];
                const bool fire = m > 0.3f;
                sp = fire ? 1.0f : 0.0f;
                u64 bal = __ballot(fire);
                if ((tid & 63) == tt) word0 = bal;
            }
            cm = m; cs = sp;
        }
        __syncthreads();
        if (wm == 1) {
#pragma unroll
            for (int ni = 0; ni < 2; ++ni)
#pragma unroll
                for (int mi = 0; mi < 2; ++mi)
#pragma unroll
                    for (int r = 0; r < 16; ++r) {
                        const int tt = mi * 32 + (r & 3) + 8 * (r >> 2) + 4 * kh;
                        If[wn * 4096 + tt * 64 + ni * 32 + l31] = acc[mi][ni][r];
                    }
        }
        __syncthreads();
        if (tid < 128) {
            float m = cm, sp = cs;
#pragma unroll 4
            for (int tt = 0; tt < 64; ++tt) {
                m = m * 0.5f * (1.0f - sp) + Ifb[tt * 64 + scol];
                const bool fire = m > 0.3f;
                sp = fire ? 1.0f : 0.0f;
                u64 bal = __ballot(fire);
                if ((tid & 63) == tt) word1 = bal;
            }
            cm = m; cs = sp;
            u64* dst = bitsOut + ((size_t)s * B_ + b) * 2048;
            const int j8 = (nb >> 6) + (tid >> 6);
            const int t0 = tid & 63, t1 = 64 + (tid & 63);
            dst[t0 * 16 + (j8 ^ (t0 & 15))] = word0;
            dst[t1 * 16 + (j8 ^ (t1 & 15))] = word1;
        }
        __syncthreads();                 // If reads done before next slice dump
    }
#undef LOADF
#undef COMPUTEF
}

// ---------- bit-layers (r21 verbatim): 2x2 ownership, register weight queue ----------
template<bool WRITE_BITS>
__global__ __launch_bounds__(256, 2)
void snn_layer_bits(const u64* __restrict__ bitsIn,
                    const bf16* __restrict__ WFh, const bf16* __restrict__ WFl,
                    u64* __restrict__ bitsOut, float* __restrict__ outp, int N)
{
    constexpr int K = 1024, KC = K / 16;        // 64 k-chunks, 16 pairs
    __shared__ char smem[49152];
    char* bitsLds = smem;                       // [0,16K): bit tile [128 t][16 u64]
    float* If = (float*)(smem + 16384);         // [16K,48K): epilogue [2][64][64]

    const int tid = threadIdx.x, lane = tid & 63, w = tid >> 6;
    const int wm = w & 1, wn = w >> 1;
    const int l31 = lane & 31, kh = lane >> 5;
    const int b = blockIdx.y;
    const int nb = blockIdx.x * 128;

    const size_t fb0 = ((size_t)((nb >> 5) + wn * 2) * KC) * 512 + (size_t)lane * 8;
    const size_t fb1 = fb0 + (size_t)KC * 512;
    const bf16* h0 = WFh + fb0;
    const bf16* h1 = WFh + fb1;
    const bf16* l0 = WFl + fb0;
    const bf16* l1 = WFl + fb1;

    const int sh8 = 8 * kh, s15 = l31 & 15;
    const int rA0b = (wm * 64 + l31) * 128;
    const int rA1b = (wm * 64 + 32 + l31) * 128;

    float cm = 0.f, cs = 0.f;
    const int scol = tid & 63;
    float* Ifb = If + (tid >> 6) * 4096;

#define LOADQ(sl, kc)                                                          \
    do {                                                                       \
        q0h[sl] = *(const bf16x8*)(h0 + (size_t)(kc) * 512);                   \
        q1h[sl] = *(const bf16x8*)(h1 + (size_t)(kc) * 512);                   \
        q0l[sl] = *(const bf16x8*)(l0 + (size_t)(kc) * 512);                   \
        q1l[sl] = *(const bf16x8*)(l1 + (size_t)(kc) * 512);                   \
    } while (0)

#define JSTEP(j, CB0, CB1)                                                     \
    do {                                                                       \
        bf16x8 a0 = expand8((unsigned)((CB0) >> (16 * (j) + sh8)) & 0xFFu);    \
        bf16x8 a1 = expand8((unsigned)((CB1) >> (16 * (j) + sh8)) & 0xFFu);    \
        acc[0][0] = MFMA32(a0, q0h[j], acc[0][0]);                             \
        acc[1][0] = MFMA32(a1, q0h[j], acc[1][0]);                             \
        acc[0][1] = MFMA32(a0, q1h[j], acc[0][1]);                             \
        acc[1][1] = MFMA32(a1, q1h[j], acc[1][1]);                             \
        acc[0][0] = MFMA32(a0, q0l[j], acc[0][0]);                             \
        acc[1][0] = MFMA32(a1, q0l[j], acc[1][0]);                             \
        acc[0][1] = MFMA32(a0, q1l[j], acc[0][1]);                             \
        acc[1][1] = MFMA32(a1, q1l[j], acc[1][1]);                             \
    } while (0)

#pragma unroll 1
    for (int s = 0; s < T_ / TS_; ++s) {
        {
            const char* src = (const char*)bitsIn + ((size_t)s * B_ + b) * 16384;
#pragma unroll
            for (int i = 0; i < 4; ++i)
                GL2LDS(src + (w * 4 + i) * 1024 + lane * 16,
                       bitsLds + (w * 4 + i) * 1024);
        }
        WAIT_BARRIER();                 // bits visible to all waves

        f32x16 acc[2][2] = {};
        bf16x8 q0h[4], q0l[4], q1h[4], q1l[4];

        LOADQ(0, 0);
        LOADQ(1, 1);
        u64 cb0 = *(const u64*)(bitsLds + rA0b + ((0 ^ s15) << 3));
        u64 cb1 = *(const u64*)(bitsLds + rA1b + ((0 ^ s15) << 3));

#pragma unroll 1
        for (int pi = 0; pi < 15; ++pi) {
            const u64 nb0 = *(const u64*)(bitsLds + rA0b + (((pi + 1) ^ s15) << 3));
            const u64 nb1 = *(const u64*)(bitsLds + rA1b + (((pi + 1) ^ s15) << 3));
            const int kc = pi * 4;
            LOADQ(2, kc + 2); JSTEP(0, cb0, cb1);
            LOADQ(3, kc + 3); JSTEP(1, cb0, cb1);
            LOADQ(0, kc + 4); JSTEP(2, cb0, cb1);
            LOADQ(1, kc + 5); JSTEP(3, cb0, cb1);
            cb0 = nb0; cb1 = nb1;
        }
        LOADQ(2, 62); JSTEP(0, cb0, cb1);
        LOADQ(3, 63); JSTEP(1, cb0, cb1);
        JSTEP(2, cb0, cb1);
        JSTEP(3, cb0, cb1);

        // ---- epilogue: 2-phase LIF scan ----
        u64 word0 = 0, word1 = 0;
        if (wm == 0) {
#pragma unroll
            for (int ni = 0; ni < 2; ++ni)
#pragma unroll
                for (int mi = 0; mi < 2; ++mi)
#pragma unroll
                    for (int r = 0; r < 16; ++r) {
                        const int tt = mi * 32 + (r & 3) + 8 * (r >> 2) + 4 * kh;
                        If[wn * 4096 + tt * 64 + ni * 32 + l31] = acc[mi][ni][r];
                    }
        }
        __syncthreads();
        if (tid < 128) {
            float m = cm, sp = cs;
#pragma unroll 4
            for (int tt = 0; tt < 64; ++tt) {
                m = m * 0.5f * (1.0f - sp) + Ifb[tt * 64 + scol];
                const bool fire = m > 0.3f;
                sp = fire ? 1.0f : 0.0f;
                if constexpr (WRITE_BITS) {
                    u64 bal = __ballot(fire);
                    if ((tid & 63) == tt) word0 = bal;
                }
            }
            cm = m; cs = sp;
        }
        __syncthreads();
        if (wm == 1) {
#pragma unroll
            for (int ni = 0; ni < 2; ++ni)
#pragma unroll
                for (int mi = 0; mi < 2; ++mi)
#pragma unroll
                    for (int r = 0; r < 16; ++r) {
                        const int tt = mi * 32 + (r & 3) + 8 * (r >> 2) + 4 * kh;
                        If[wn * 4096 + tt * 64 + ni * 32 + l31] = acc[mi][ni][r];
                    }
        }
        __syncthreads();
        if (tid < 128) {
            float m = cm, sp = cs;
#pragma unroll 4
            for (int tt = 0; tt < 64; ++tt) {
                m = m * 0.5f * (1.0f - sp) + Ifb[tt * 64 + scol];
                const bool fire = m > 0.3f;
                sp = fire ? 1.0f : 0.0f;
                if constexpr (WRITE_BITS) {
                    u64 bal = __ballot(fire);
                    if ((tid & 63) == tt) word1 = bal;
                }
            }
            cm = m; cs = sp;
            if constexpr (WRITE_BITS) {
                u64* dst = bitsOut + ((size_t)s * B_ + b) * 2048;
                const int j8 = (nb >> 6) + (tid >> 6);
                const int t0 = tid & 63, t1 = 64 + (tid & 63);
                dst[t0 * 16 + (j8 ^ (t0 & 15))] = word0;
                dst[t1 * 16 + (j8 ^ (t1 & 15))] = word1;
            } else {
                if (s == T_ / TS_ - 1)
                    outp[(size_t)b * N + nb + tid] = cs;   // spike at t=511
            }
        }
        __syncthreads();                 // If reads done before next slice
    }
#undef LOADQ
#undef JSTEP
}

extern "C" void kernel_launch(void* const* d_in, const int* in_sizes, int n_in,
                              void* d_out, int out_size, void* d_ws, size_t ws_size,
                              hipStream_t stream)
{
    const float* x  = (const float*)d_in[0];
    const float* w0 = (const float*)d_in[1];
    const float* w1 = (const float*)d_in[2];
    const float* w2 = (const float*)d_in[3];
    float* out = (float*)d_out;

    char* p = (char*)d_ws;
    bf16* wf0h = (bf16*)p; p += (size_t)N1_ * D0_ * 2;               // 1 MB
    bf16* wf0l = (bf16*)p; p += (size_t)N1_ * D0_ * 2;
    bf16* wf1h = (bf16*)p; p += (size_t)N2_ * N1_ * 2;               // 2 MB
    bf16* wf1l = (bf16*)p; p += (size_t)N2_ * N1_ * 2;
    bf16* wf2h = (bf16*)p; p += (size_t)N3_ * N2_ * 2;               // 1 MB
    bf16* wf2l = (bf16*)p; p += (size_t)N3_ * N2_ * 2;
    bf16* XFh  = (bf16*)p; p += (size_t)T_ * B_ * D0_ * 2;           // 67 MB
    bf16* XFl  = (bf16*)p; p += (size_t)T_ * B_ * D0_ * 2;           // 67 MB
    u64* bits0 = (u64*)p;  p += (size_t)(T_/TS_) * B_ * TS_ * (N1_/8);  // 8.4 MB
    u64* bits1 = (u64*)p;  p += (size_t)(T_/TS_) * B_ * TS_ * (N2_/8);  // 8.4 MB

    split_wf<<<dim3(D0_/16, N1_/32), 64, 0, stream>>>(w0, wf0h, wf0l, D0_, N1_);
    split_wf<<<dim3(N1_/16, N2_/32), 64, 0, stream>>>(w1, wf1h, wf1l, N1_, N2_);
    split_wf<<<dim3(N2_/16, N3_/32), 64, 0, stream>>>(w2, wf2h, wf2l, N2_, N3_);
    split_xf<<<dim3(32, 4, (T_/TS_) * B_), 64, 0, stream>>>(x, XFh, XFl);

    // L0: XF@WF0 (3-term, direct-register) + LIF -> bit train
    snn_layer0<<<dim3(B_ * (N1_/128)), 256, 0, stream>>>(XFh, XFl, wf0h, wf0l, bits0);
    // L1: bits0@w1 + LIF -> bit train
    snn_layer_bits<true ><<<dim3(N2_/128, B_), 256, 0, stream>>>(
        bits0, wf1h, wf1l, bits1, nullptr, N2_);
    // L2: bits1@w2 + LIF -> final spikes to d_out
    snn_layer_bits<false><<<dim3(N3_/128, B_), 256, 0, stream>>>(
        bits1, wf2h, wf2l, nullptr, out, N3_);
}